// Round 8
// baseline (474.677 us; speedup 1.0000x reference)
//
#include <hip/hip_runtime.h>
#include <math.h>

// Problem constants
#define TT 16384   // tokens
#define HH 2048    // hidden
#define EE 64      // experts
#define KK 8       // top_k

#define TB 32          // tokens per block
#define HC 64          // h per chunk
#define NCH (HH / HC)  // 32 chunks
#define TOPC 10        // fp32 candidate count for fixup
#define MARGIN 4e-6f   // selection-score gap below which we fp64-verify

// Output layout (flat float32):
// probs [TT][KK] | indices [TT][KK] | map [TT][EE] | aux scalar
#define IDX_OFF ((size_t)TT * KK)
#define MAP_OFF ((size_t)2 * TT * KK)
#define AUX_OFF ((size_t)2 * TT * KK + (size_t)TT * EE)

// LDS: double-buffered staging, 24576 B per buffer:
//   stH: 32 rows x 16 float4 slots (8192 B) at buf+0
//   stW: 64 rows x 16 float4 slots (16384 B) at buf+8192
// Swizzled layout: slot (r, y) holds row r's global float4-group (y ^ (r&7)).
// Writer: thread (ts,xs) LOADS global group xs^(ts&7), WRITES slot (ts, xs).
// (R7 bug: wrote slot xs^(ts&7) too -> XORs cancelled -> linear layout vs
//  swizzled reads -> mismatched K-slices. Rule #21: both sides or neither.)
#define BUFB 24576
#define RSTRIDE 66
#define BFLOATS 2120

__global__ __launch_bounds__(256, 3)
void router_kernel(const float* __restrict__ hidden,
                   const float* __restrict__ gate_w,
                   const float* __restrict__ bias,
                   float* __restrict__ out)
{
    __shared__ float smem[2 * BUFB / 4];   // 49152 B

    const int tid  = threadIdx.x;
    const int w    = tid >> 6;       // wave 0..3
    const int lane = tid & 63;
    const int s    = tid >> 5;       // h-split 0..7 (half-wave)
    const int p    = tid & 31;
    const int tg   = p >> 3;         // tokens tg + 4i, i=0..7
    const int eg   = p & 7;          // experts eg + 8j, j=0..7
    const int tok0 = blockIdx.x * TB;

    // staging coords: thread owns slot (ts, xs) of rows ts, ts+16k
    const int xs  = tid & 15;
    const int ts  = tid >> 4;        // 0..15
    const int col = 4 * (xs ^ (ts & 7));   // swizzled global column; (ts+16k)&7 == ts&7

    const float* hP = hidden + (size_t)(tok0 + ts) * HH + col;
    const float* wP = gate_w + (size_t)ts * HH + col;
    const int wrBase = (ts * 16 + xs) * 16;   // LDS byte offset of slot (ts, xs)  [THE FIX]

    float acc[8][8];
    #pragma unroll
    for (int i = 0; i < 8; ++i)
        #pragma unroll
        for (int j = 0; j < 8; ++j) acc[i][j] = 0.0f;

    // prologue: load chunk 0 into registers
    float4 hv0 = *reinterpret_cast<const float4*>(hP);
    float4 hv1 = *reinterpret_cast<const float4*>(hP + (size_t)16 * HH);
    float4 wv0 = *reinterpret_cast<const float4*>(wP);
    float4 wv1 = *reinterpret_cast<const float4*>(wP + (size_t)16 * HH);
    float4 wv2 = *reinterpret_cast<const float4*>(wP + (size_t)32 * HH);
    float4 wv3 = *reinterpret_cast<const float4*>(wP + (size_t)48 * HH);

    #pragma unroll 2
    for (int c = 0; c < NCH; ++c) {
        // ds_write chunk c (regs) into buf[c&1]
        {
            char* wb_ = (char*)smem + (c & 1) * BUFB + wrBase;
            *reinterpret_cast<float4*>(wb_ + 0)     = hv0;
            *reinterpret_cast<float4*>(wb_ + 4096)  = hv1;
            *reinterpret_cast<float4*>(wb_ + 8192)  = wv0;
            *reinterpret_cast<float4*>(wb_ + 12288) = wv1;
            *reinterpret_cast<float4*>(wb_ + 16384) = wv2;
            *reinterpret_cast<float4*>(wb_ + 20480) = wv3;
        }
        __syncthreads();   // buf[c&1] visible; prev compute (buf[(c-1)&1]) done

        // issue next chunk's loads (land during this chunk's compute)
        if (c + 1 < NCH) {
            const int o = (c + 1) * HC;
            hv0 = *reinterpret_cast<const float4*>(hP + o);
            hv1 = *reinterpret_cast<const float4*>(hP + (size_t)16 * HH + o);
            wv0 = *reinterpret_cast<const float4*>(wP + o);
            wv1 = *reinterpret_cast<const float4*>(wP + (size_t)16 * HH + o);
            wv2 = *reinterpret_cast<const float4*>(wP + (size_t)32 * HH + o);
            wv3 = *reinterpret_cast<const float4*>(wP + (size_t)48 * HH + o);
        }

        // compute: split s covers f4-groups {2s, 2s+1}; 8 tok x 8 exp tile
        const char* rb = (const char*)smem + (c & 1) * BUFB;
        #pragma unroll
        for (int u = 0; u < 2; ++u) {
            const int f4r = 2 * s + u;
            const int cH  = f4r ^ tg;          // slot for rows with (r&7)==tg
            const char* hA = rb + tg * 256 + cH * 16;
            const char* hB = rb + tg * 256 + (cH ^ 4) * 16;  // rows with (r&7)==tg^4
            float4 ha[8];
            #pragma unroll
            for (int i = 0; i < 8; ++i)
                ha[i] = *reinterpret_cast<const float4*>(
                    ((i & 1) ? hB : hA) + i * 1024);   // row tg + 4i

            const char* wBp = rb + 8192 + eg * 256 + (f4r ^ eg) * 16;
            #pragma unroll
            for (int g = 0; g < 2; ++g) {
                float4 wq[4];
                #pragma unroll
                for (int jj = 0; jj < 4; ++jj)
                    wq[jj] = *reinterpret_cast<const float4*>(
                        wBp + (4 * g + jj) * 2048);    // row eg + 8*(4g+jj)
                #pragma unroll
                for (int i = 0; i < 8; ++i)
                    #pragma unroll
                    for (int jj = 0; jj < 4; ++jj) {
                        float a_ = acc[i][4 * g + jj];
                        a_ = fmaf(ha[i].x, wq[jj].x, a_);
                        a_ = fmaf(ha[i].y, wq[jj].y, a_);
                        a_ = fmaf(ha[i].z, wq[jj].z, a_);
                        a_ = fmaf(ha[i].w, wq[jj].w, a_);
                        acc[i][4 * g + jj] = a_;
                    }
            }
        }
    }
    __syncthreads();   // compute done; staging area reusable

    // ---- reduce 8 h-split partials ----
    // step 1: fold half-wave pairs in-register (no barrier)
    #pragma unroll
    for (int i = 0; i < 8; ++i)
        #pragma unroll
        for (int j = 0; j < 8; ++j)
            acc[i][j] += __shfl_xor(acc[i][j], 32, 64);
    // lanes<32 of wave w hold partial for split-pair w

    float* B0 = smem;
    float* B1 = smem + BFLOATS;
    // layout: B[tok*66 + eg*8 + j]  (expert e=eg+8j at slot eg*8+j)

    if (lane < 32 && w >= 2) {
        float* buf = (w == 2) ? B0 : B1;
        #pragma unroll
        for (int i = 0; i < 8; ++i) {
            float* row = buf + (tg + 4 * i) * RSTRIDE + eg * 8;
            *reinterpret_cast<float4*>(row) =
                make_float4(acc[i][0], acc[i][1], acc[i][2], acc[i][3]);
            *reinterpret_cast<float4*>(row + 4) =
                make_float4(acc[i][4], acc[i][5], acc[i][6], acc[i][7]);
        }
    }
    __syncthreads();
    if (lane < 32 && w < 2) {
        const float* buf = (w == 0) ? B0 : B1;
        #pragma unroll
        for (int i = 0; i < 8; ++i) {
            const float* row = buf + (tg + 4 * i) * RSTRIDE + eg * 8;
            float4 lo = *reinterpret_cast<const float4*>(row);
            float4 hi = *reinterpret_cast<const float4*>(row + 4);
            acc[i][0] += lo.x; acc[i][1] += lo.y;
            acc[i][2] += lo.z; acc[i][3] += lo.w;
            acc[i][4] += hi.x; acc[i][5] += hi.y;
            acc[i][6] += hi.z; acc[i][7] += hi.w;
        }
    }
    __syncthreads();
    if (lane < 32 && w == 1) {
        #pragma unroll
        for (int i = 0; i < 8; ++i) {
            float* row = B0 + (tg + 4 * i) * RSTRIDE + eg * 8;
            *reinterpret_cast<float4*>(row) =
                make_float4(acc[i][0], acc[i][1], acc[i][2], acc[i][3]);
            *reinterpret_cast<float4*>(row + 4) =
                make_float4(acc[i][4], acc[i][5], acc[i][6], acc[i][7]);
        }
    }
    __syncthreads();
    if (lane < 32 && w == 0) {
        #pragma unroll
        for (int i = 0; i < 8; ++i) {
            float* row0 = B0 + (tg + 4 * i) * RSTRIDE + eg * 8;
            float* row1 = B1 + (tg + 4 * i) * RSTRIDE + eg * 8;
            float4 lo = *reinterpret_cast<const float4*>(row0);
            float4 hi = *reinterpret_cast<const float4*>(row0 + 4);
            *reinterpret_cast<float4*>(row1) =
                make_float4(acc[i][0] + lo.x, acc[i][1] + lo.y,
                            acc[i][2] + lo.z, acc[i][3] + lo.w);
            *reinterpret_cast<float4*>(row1 + 4) =
                make_float4(acc[i][4] + hi.x, acc[i][5] + hi.y,
                            acc[i][6] + hi.z, acc[i][7] + hi.w);
        }
    }
    __syncthreads();

    // ---- epilogue: 8 lanes per token; logits (slot layout) in B1 ----
    const int t = tid >> 3;   // 0..31
    const int q = tid & 7;    // lane owns experts q + 8i (slot q*8+i)
    const int tok = tok0 + t;

    float lv[8];
    {
        float4 v0 = *reinterpret_cast<const float4*>(B1 + t * RSTRIDE + q * 8);
        float4 v1 = *reinterpret_cast<const float4*>(B1 + t * RSTRIDE + q * 8 + 4);
        lv[0] = v0.x; lv[1] = v0.y; lv[2] = v0.z; lv[3] = v0.w;
        lv[4] = v1.x; lv[5] = v1.y; lv[6] = v1.z; lv[7] = v1.w;
    }

    float mx = lv[0];
    #pragma unroll
    for (int i = 1; i < 8; ++i) mx = fmaxf(mx, lv[i]);
    #pragma unroll
    for (int sh = 1; sh < 8; sh <<= 1) mx = fmaxf(mx, __shfl_xor(mx, sh, 64));

    float ex[8], psum = 0.0f;
    #pragma unroll
    for (int i = 0; i < 8; ++i) { ex[i] = expf(lv[i] - mx); psum += ex[i]; }
    #pragma unroll
    for (int sh = 1; sh < 8; sh <<= 1) psum += __shfl_xor(psum, sh, 64);
    const float inv = 1.0f / psum;

    float pr[8], selv[8];
    #pragma unroll
    for (int i = 0; i < 8; ++i) {
        pr[i]   = ex[i] * inv;
        selv[i] = pr[i] + bias[q + 8 * i];
    }

    // top-10 candidates (fp32), strict-> with lowest-index tie-break
    float ws[TOPC], wp[TOPC];
    int   wi[TOPC];
    #pragma unroll
    for (int k = 0; k < TOPC; ++k) {
        float bs = selv[0], bp = pr[0];
        int bi = q;
        #pragma unroll
        for (int i = 1; i < 8; ++i)
            if (selv[i] > bs) { bs = selv[i]; bp = pr[i]; bi = q + 8 * i; }
        #pragma unroll
        for (int sh = 1; sh < 8; sh <<= 1) {
            float os = __shfl_xor(bs, sh, 64);
            float op = __shfl_xor(bp, sh, 64);
            int   ob = __shfl_xor(bi, sh, 64);
            if (os > bs || (os == bs && ob < bi)) { bs = os; bp = op; bi = ob; }
        }
        ws[k] = bs; wp[k] = bp; wi[k] = bi;
        #pragma unroll
        for (int i = 0; i < 8; ++i)
            if (q + 8 * i == bi) selv[i] = -INFINITY;
    }

    // flag: any adjacent gap among ranks 1..9 too small to trust fp32
    bool flag = false;
    #pragma unroll
    for (int k = 0; k < 8; ++k)
        flag = flag || (ws[k] - ws[k + 1] < MARGIN);

    if (flag) {   // uniform across the 8-lane token group
        const float* hrow = hidden + (size_t)tok * HH;
        const float* wr[TOPC];
        #pragma unroll
        for (int k = 0; k < TOPC; ++k) wr[k] = gate_w + (size_t)wi[k] * HH;

        double l64[TOPC];
        #pragma unroll
        for (int k = 0; k < TOPC; ++k) l64[k] = 0.0;

        for (int m = 0; m < 64; ++m) {
            float4 h4 = *reinterpret_cast<const float4*>(hrow + m * 32 + 4 * q);
            double h0 = h4.x, h1 = h4.y, h2 = h4.z, h3 = h4.w;
            #pragma unroll
            for (int k = 0; k < TOPC; ++k) {
                float4 w4 = *reinterpret_cast<const float4*>(wr[k] + m * 32 + 4 * q);
                l64[k] = fma(h0, (double)w4.x, l64[k]);
                l64[k] = fma(h1, (double)w4.y, l64[k]);
                l64[k] = fma(h2, (double)w4.z, l64[k]);
                l64[k] = fma(h3, (double)w4.w, l64[k]);
            }
        }
        #pragma unroll
        for (int k = 0; k < TOPC; ++k)
            #pragma unroll
            for (int sh = 1; sh < 8; sh <<= 1)
                l64[k] += __shfl_xor(l64[k], sh, 64);

        // exact-rank selection scores (common positive rescale; bias exact)
        double s64[TOPC];
        #pragma unroll
        for (int k = 0; k < TOPC; ++k)
            s64[k] = exp(l64[k] - (double)mx) * (double)inv + (double)bias[wi[k]];

        // order first 8 by (score desc, idx asc) - static indices only
        #pragma unroll
        for (int a = 0; a < 8; ++a) {
            #pragma unroll
            for (int b = a + 1; b < TOPC; ++b) {
                bool sw = (s64[b] > s64[a]) ||
                          (s64[b] == s64[a] && wi[b] < wi[a]);
                if (sw) {
                    double td = s64[a]; s64[a] = s64[b]; s64[b] = td;
                    int    ti = wi[a];  wi[a]  = wi[b];  wi[b]  = ti;
                    float  tp = wp[a];  wp[a]  = wp[b];  wp[b]  = tp;
                }
            }
        }
    }

    // ---- common write-out (wi/wp[0..7] final) ----
    int oi = wi[0];
    float opf = wp[0];
    #pragma unroll
    for (int k = 1; k < 8; ++k)
        if (q == k) { oi = wi[k]; opf = wp[k]; }

    float ps = 0.0f;
    #pragma unroll
    for (int k = 0; k < 8; ++k) ps += wp[k];
    const float rinv = 1.0f / (ps + 1e-9f);

    out[(size_t)tok * KK + q]           = opf * rinv;
    out[IDX_OFF + (size_t)tok * KK + q] = (float)oi;

    unsigned long long mk = 0ull;
    #pragma unroll
    for (int k = 0; k < 8; ++k) mk |= (1ull << wi[k]);

    {
        float4 a, b;
        a.x = ((mk >> (8 * q + 0)) & 1ull) ? 1.0f : 0.0f;
        a.y = ((mk >> (8 * q + 1)) & 1ull) ? 1.0f : 0.0f;
        a.z = ((mk >> (8 * q + 2)) & 1ull) ? 1.0f : 0.0f;
        a.w = ((mk >> (8 * q + 3)) & 1ull) ? 1.0f : 0.0f;
        b.x = ((mk >> (8 * q + 4)) & 1ull) ? 1.0f : 0.0f;
        b.y = ((mk >> (8 * q + 5)) & 1ull) ? 1.0f : 0.0f;
        b.z = ((mk >> (8 * q + 6)) & 1ull) ? 1.0f : 0.0f;
        b.w = ((mk >> (8 * q + 7)) & 1ull) ? 1.0f : 0.0f;
        float* mo = out + MAP_OFF + (size_t)tok * EE + 8 * q;
        reinterpret_cast<float4*>(mo)[0] = a;
        reinterpret_cast<float4*>(mo)[1] = b;
    }

    if (blockIdx.x == 0 && tid == 0) out[AUX_OFF] = 0.0f;
}

extern "C" void kernel_launch(void* const* d_in, const int* in_sizes, int n_in,
                              void* d_out, int out_size, void* d_ws, size_t ws_size,
                              hipStream_t stream) {
    const float* hidden = (const float*)d_in[0];  // [16384, 2048] f32
    const float* gate_w = (const float*)d_in[1];  // [64, 2048] f32
    const float* bias   = (const float*)d_in[2];  // [64] f32
    float* out = (float*)d_out;

    router_kernel<<<TT / TB, 256, 0, stream>>>(hidden, gate_w, bias, out);
}

// Round 9
// 129.580 us; speedup vs baseline: 3.6632x; 3.6632x over previous
//
#include <hip/hip_runtime.h>
#include <math.h>

// Problem constants
#define TT 16384   // tokens
#define HH 2048    // hidden
#define EE 64      // experts
#define KK 8       // top_k

#define TB 16          // tokens per block
#define HC 64          // h per chunk
#define NCH (HH / HC)  // 32 chunks
#define TOPC 10        // fp32 candidate count for fixup
#define MARGIN 2.5e-5f // selection-score gap below which we fp64-verify

// Output layout (flat float32):
// probs [TT][KK] | indices [TT][KK] | map [TT][EE] | aux scalar
#define IDX_OFF ((size_t)TT * KK)
#define MAP_OFF ((size_t)2 * TT * KK)
#define AUX_OFF ((size_t)2 * TT * KK + (size_t)TT * EE)

// LDS: double-buffered, BUFB bytes per buffer. Plane byte offsets in buffer:
//   Whi [64 rows][128 B] @ 0      Wlo @ 8192
//   Hhi [16 rows][128 B] @ 16384  Hlo @ 18432
// Swizzle (BOTH write and read sides, rule #21): within each 128 B row,
// byte o stored/fetched at o ^ ((row & 7) << 4).
#define WHI 0
#define WLO 8192
#define HHI 16384
#define HLO 18432
#define BUFB 20480

typedef short bf16x8 __attribute__((ext_vector_type(8)));
typedef float f32x4  __attribute__((ext_vector_type(4)));

__device__ __forceinline__ unsigned short f2bf(float x) {   // RNE fp32->bf16
    unsigned int u = __float_as_uint(x);
    u += 0x7FFFu + ((u >> 16) & 1u);
    return (unsigned short)(u >> 16);
}
__device__ __forceinline__ float bf2f(unsigned short b) {
    return __uint_as_float(((unsigned int)b) << 16);
}
__device__ __forceinline__ void cvt4(const float4 v, ushort4* hi, ushort4* lo) {
    unsigned short h0 = f2bf(v.x), h1 = f2bf(v.y),
                   h2 = f2bf(v.z), h3 = f2bf(v.w);
    *hi = make_ushort4(h0, h1, h2, h3);
    *lo = make_ushort4(f2bf(v.x - bf2f(h0)), f2bf(v.y - bf2f(h1)),
                       f2bf(v.z - bf2f(h2)), f2bf(v.w - bf2f(h3)));
}

__global__ __launch_bounds__(256, 4)
void router_kernel(const float* __restrict__ hidden,
                   const float* __restrict__ gate_w,
                   const float* __restrict__ bias,
                   float* __restrict__ out)
{
    __shared__ __align__(16) unsigned char smem[2 * BUFB];   // 40 KB

    const int tid  = threadIdx.x;
    const int tok0 = blockIdx.x * TB;

    // ---- staging coords ----
    const int wr  = tid >> 2;   // W row (expert) 0..63
    const int cg  = tid & 3;    // W col-group: col4 = cg*4+m, m=0..3
    const int hr  = tid >> 4;   // H row (token) 0..15
    const int hc4 = tid & 15;   // H col4 0..15

    const float* wgp = gate_w + (size_t)wr * HH + cg * 16;
    const float* hgp = hidden + (size_t)(tok0 + hr) * HH + hc4 * 4;

    const int wxor = (wr & 7) << 4;
    const int wOff0 = wr * 128 + (((cg * 4 + 0) * 8) ^ wxor);
    const int wOff1 = wr * 128 + (((cg * 4 + 1) * 8) ^ wxor);
    const int wOff2 = wr * 128 + (((cg * 4 + 2) * 8) ^ wxor);
    const int wOff3 = wr * 128 + (((cg * 4 + 3) * 8) ^ wxor);
    const int hOff  = hr * 128 + ((hc4 * 8) ^ ((hr & 7) << 4));

    // ---- fragment read offsets (per lane) ----
    // A-frag: hidden row rx, k-bytes ks*64 + kq*16 (any k-perm cancels A vs B)
    const int lane = tid & 63;
    const int e0   = (tid >> 6) * 16;   // wave's expert tile base
    const int rx   = lane & 15;
    const int kq   = lane >> 4;
    const int rxor = (rx & 7) << 4;
    const int aOff0 = rx * 128 + ((kq * 16) ^ rxor);
    const int aOff1 = aOff0 ^ 64;                       // ks=1 flips byte bit 6
    const int bOff0 = (e0 + rx) * 128 + ((kq * 16) ^ rxor);  // (e0+rx)&7 == rx&7
    const int bOff1 = bOff0 ^ 64;

    f32x4 acc = {0.f, 0.f, 0.f, 0.f};

    // prologue: chunk-0 globals
    float4 hv  = *(const float4*)(hgp);
    float4 wv0 = *(const float4*)(wgp + 0);
    float4 wv1 = *(const float4*)(wgp + 4);
    float4 wv2 = *(const float4*)(wgp + 8);
    float4 wv3 = *(const float4*)(wgp + 12);

    #pragma unroll 2
    for (int c = 0; c < NCH; ++c) {
        unsigned char* buf = smem + (c & 1) * BUFB;

        // stage chunk c (convert fp32 -> bf16 hi/lo, swizzled ds_write)
        ushort4 hi, lo;
        cvt4(hv,  &hi, &lo);
        *(ushort4*)(buf + HHI + hOff)  = hi;
        *(ushort4*)(buf + HLO + hOff)  = lo;
        cvt4(wv0, &hi, &lo);
        *(ushort4*)(buf + WHI + wOff0) = hi;
        *(ushort4*)(buf + WLO + wOff0) = lo;
        cvt4(wv1, &hi, &lo);
        *(ushort4*)(buf + WHI + wOff1) = hi;
        *(ushort4*)(buf + WLO + wOff1) = lo;
        cvt4(wv2, &hi, &lo);
        *(ushort4*)(buf + WHI + wOff2) = hi;
        *(ushort4*)(buf + WLO + wOff2) = lo;
        cvt4(wv3, &hi, &lo);
        *(ushort4*)(buf + WHI + wOff3) = hi;
        *(ushort4*)(buf + WLO + wOff3) = lo;

        __syncthreads();   // buf[c&1] visible; also fences buffer reuse (see R9 notes)

        // prefetch chunk c+1 globals (land under MFMA)
        if (c + 1 < NCH) {
            const int o = (c + 1) * HC;
            hv  = *(const float4*)(hgp + o);
            wv0 = *(const float4*)(wgp + o + 0);
            wv1 = *(const float4*)(wgp + o + 4);
            wv2 = *(const float4*)(wgp + o + 8);
            wv3 = *(const float4*)(wgp + o + 12);
        }

        // compute: 2 k-steps x 3 MFMA (bf16x3: hi*lo + lo*hi + hi*hi)
        {
            bf16x8 Ah = *(const bf16x8*)(buf + HHI + aOff0);
            bf16x8 Al = *(const bf16x8*)(buf + HLO + aOff0);
            bf16x8 Bh = *(const bf16x8*)(buf + WHI + bOff0);
            bf16x8 Bl = *(const bf16x8*)(buf + WLO + bOff0);
            acc = __builtin_amdgcn_mfma_f32_16x16x32_bf16(Ah, Bl, acc, 0, 0, 0);
            acc = __builtin_amdgcn_mfma_f32_16x16x32_bf16(Al, Bh, acc, 0, 0, 0);
            acc = __builtin_amdgcn_mfma_f32_16x16x32_bf16(Ah, Bh, acc, 0, 0, 0);
        }
        {
            bf16x8 Ah = *(const bf16x8*)(buf + HHI + aOff1);
            bf16x8 Al = *(const bf16x8*)(buf + HLO + aOff1);
            bf16x8 Bh = *(const bf16x8*)(buf + WHI + bOff1);
            bf16x8 Bl = *(const bf16x8*)(buf + WLO + bOff1);
            acc = __builtin_amdgcn_mfma_f32_16x16x32_bf16(Ah, Bl, acc, 0, 0, 0);
            acc = __builtin_amdgcn_mfma_f32_16x16x32_bf16(Al, Bh, acc, 0, 0, 0);
            acc = __builtin_amdgcn_mfma_f32_16x16x32_bf16(Ah, Bh, acc, 0, 0, 0);
        }
    }

    // ---- logits to LDS (overlay buf0 front; disjoint from buf1 in-flight) ----
    // D layout (m89-verified): col = lane&15 (expert), row = 4*(lane>>4)+r (token)
    float* lg = (float*)smem;   // [16][68]
    #pragma unroll
    for (int r = 0; r < 4; ++r)
        lg[(4 * kq + r) * 68 + e0 + rx] = acc[r];
    __syncthreads();

    // ---- epilogue: 16 lanes per token (R6-validated machinery) ----
    const int t   = tid >> 4;   // 0..15
    const int q   = tid & 15;   // lane owns experts q + 16i, i=0..3
    const int tok = tok0 + t;

    float lv[4];
    #pragma unroll
    for (int i = 0; i < 4; ++i) lv[i] = lg[t * 68 + q + 16 * i];

    float mx = lv[0];
    #pragma unroll
    for (int i = 1; i < 4; ++i) mx = fmaxf(mx, lv[i]);
    #pragma unroll
    for (int sh = 1; sh < 16; sh <<= 1) mx = fmaxf(mx, __shfl_xor(mx, sh, 64));

    float ex[4], psum = 0.0f;
    #pragma unroll
    for (int i = 0; i < 4; ++i) { ex[i] = expf(lv[i] - mx); psum += ex[i]; }
    #pragma unroll
    for (int sh = 1; sh < 16; sh <<= 1) psum += __shfl_xor(psum, sh, 64);
    const float inv = 1.0f / psum;

    float pr[4], selv[4];
    #pragma unroll
    for (int i = 0; i < 4; ++i) {
        pr[i]   = ex[i] * inv;
        selv[i] = pr[i] + bias[q + 16 * i];
    }

    // top-10 candidates (fp32), strict-> with lowest-index tie-break
    float ws[TOPC], wp[TOPC];
    int   wi[TOPC];
    #pragma unroll
    for (int k = 0; k < TOPC; ++k) {
        float bs = selv[0], bp = pr[0];
        int bi = q;
        #pragma unroll
        for (int i = 1; i < 4; ++i)
            if (selv[i] > bs) { bs = selv[i]; bp = pr[i]; bi = q + 16 * i; }
        #pragma unroll
        for (int sh = 1; sh < 16; sh <<= 1) {
            float os = __shfl_xor(bs, sh, 64);
            float op = __shfl_xor(bp, sh, 64);
            int   ob = __shfl_xor(bi, sh, 64);
            if (os > bs || (os == bs && ob < bi)) { bs = os; bp = op; bi = ob; }
        }
        ws[k] = bs; wp[k] = bp; wi[k] = bi;
        #pragma unroll
        for (int i = 0; i < 4; ++i)
            if (q + 16 * i == bi) selv[i] = -INFINITY;
    }

    // flag: any adjacent gap among ranks 1..9 too small to trust bf16x3
    bool flag = false;
    #pragma unroll
    for (int k = 0; k < 8; ++k)
        flag = flag || (ws[k] - ws[k + 1] < MARGIN);

    if (flag) {   // uniform across the 16-lane token group
        const float* hrow = hidden + (size_t)tok * HH;
        const float* wr_[TOPC];
        #pragma unroll
        for (int k = 0; k < TOPC; ++k) wr_[k] = gate_w + (size_t)wi[k] * HH;

        double l64[TOPC];
        #pragma unroll
        for (int k = 0; k < TOPC; ++k) l64[k] = 0.0;

        for (int m = 0; m < 32; ++m) {
            float4 h4 = *(const float4*)(hrow + m * 64 + 4 * q);
            double h0 = h4.x, h1 = h4.y, h2 = h4.z, h3 = h4.w;
            #pragma unroll
            for (int k = 0; k < TOPC; ++k) {
                float4 w4 = *(const float4*)(wr_[k] + m * 64 + 4 * q);
                l64[k] = fma(h0, (double)w4.x, l64[k]);
                l64[k] = fma(h1, (double)w4.y, l64[k]);
                l64[k] = fma(h2, (double)w4.z, l64[k]);
                l64[k] = fma(h3, (double)w4.w, l64[k]);
            }
        }
        #pragma unroll
        for (int k = 0; k < TOPC; ++k)
            #pragma unroll
            for (int sh = 1; sh < 16; sh <<= 1)
                l64[k] += __shfl_xor(l64[k], sh, 64);

        // exact-rank selection scores (common positive rescale; bias exact)
        double s64[TOPC];
        #pragma unroll
        for (int k = 0; k < TOPC; ++k)
            s64[k] = exp(l64[k] - (double)mx) * (double)inv + (double)bias[wi[k]];

        // order first 8 by (score desc, idx asc) - static indices only
        #pragma unroll
        for (int a = 0; a < 8; ++a) {
            #pragma unroll
            for (int b = a + 1; b < TOPC; ++b) {
                bool sw = (s64[b] > s64[a]) ||
                          (s64[b] == s64[a] && wi[b] < wi[a]);
                if (sw) {
                    double td = s64[a]; s64[a] = s64[b]; s64[b] = td;
                    int    ti = wi[a];  wi[a]  = wi[b];  wi[b]  = ti;
                    float  tp = wp[a];  wp[a]  = wp[b];  wp[b]  = tp;
                }
            }
        }
    }

    // ---- common write-out (wi/wp[0..7] final) ----
    int oi = wi[0];
    float opf = wp[0];
    #pragma unroll
    for (int k = 1; k < 8; ++k)
        if (q == k) { oi = wi[k]; opf = wp[k]; }

    float ps = 0.0f;
    #pragma unroll
    for (int k = 0; k < 8; ++k) ps += wp[k];
    const float rinv = 1.0f / (ps + 1e-9f);

    if (q < KK) {
        out[(size_t)tok * KK + q]           = opf * rinv;
        out[IDX_OFF + (size_t)tok * KK + q] = (float)oi;
    }

    unsigned long long mk = 0ull;
    #pragma unroll
    for (int k = 0; k < 8; ++k) mk |= (1ull << wi[k]);

    {
        float4 a;
        a.x = ((mk >> (4 * q + 0)) & 1ull) ? 1.0f : 0.0f;
        a.y = ((mk >> (4 * q + 1)) & 1ull) ? 1.0f : 0.0f;
        a.z = ((mk >> (4 * q + 2)) & 1ull) ? 1.0f : 0.0f;
        a.w = ((mk >> (4 * q + 3)) & 1ull) ? 1.0f : 0.0f;
        *(float4*)(out + MAP_OFF + (size_t)tok * EE + 4 * q) = a;
    }

    if (blockIdx.x == 0 && tid == 0) out[AUX_OFF] = 0.0f;
}

extern "C" void kernel_launch(void* const* d_in, const int* in_sizes, int n_in,
                              void* d_out, int out_size, void* d_ws, size_t ws_size,
                              hipStream_t stream) {
    const float* hidden = (const float*)d_in[0];  // [16384, 2048] f32
    const float* gate_w = (const float*)d_in[1];  // [64, 2048] f32
    const float* bias   = (const float*)d_in[2];  // [64] f32
    float* out = (float*)d_out;

    router_kernel<<<TT / TB, 256, 0, stream>>>(hidden, gate_w, bias, out);
}

// Round 10
// 112.341 us; speedup vs baseline: 4.2253x; 1.1535x over previous
//
#include <hip/hip_runtime.h>
#include <math.h>

// Problem constants
#define TT 16384   // tokens
#define HH 2048    // hidden
#define EE 64      // experts
#define KK 8       // top_k

#define TB 16          // tokens per block (one MFMA M-tile)
#define HC 64          // h per chunk (2 MFMA k-steps)
#define NCH (HH / HC)  // 32 chunks
#define TOPC 10        // fp32 candidate count for fixup
#define MARGIN 2.5e-5f // selection-score gap below which we fp64-verify

// Output layout (flat float32):
// probs [TT][KK] | indices [TT][KK] | map [TT][EE] | aux scalar
#define IDX_OFF ((size_t)TT * KK)
#define MAP_OFF ((size_t)2 * TT * KK)
#define AUX_OFF ((size_t)2 * TT * KK + (size_t)TT * EE)

// d_ws layout (bf16 shorts): hi plane then lo plane, each WSPLANE shorts.
// Fragment-native: [m (k/32)][kq][e][8 j] -> element (e, k=m*32+kq*8+j)
// at  m*2048 + kq*512 + e*8 + j.  B-frag load for (tile e0, kstep m):
// lane(rx,kq) reads shorts [m][kq][e0+rx][0..8) -> 16 lanes x 16B contiguous.
#define WSPLANE 131072
#define WS_BYTES (2 * WSPLANE * 2)   // 512 KB

typedef short bf16x8 __attribute__((ext_vector_type(8)));
typedef float f32x4  __attribute__((ext_vector_type(4)));

__device__ __forceinline__ unsigned short f2bf(float x) {   // RNE fp32->bf16
    unsigned int u = __float_as_uint(x);
    u += 0x7FFFu + ((u >> 16) & 1u);
    return (unsigned short)(u >> 16);
}
__device__ __forceinline__ float bf2f(unsigned short b) {
    return __uint_as_float(((unsigned int)b) << 16);
}
__device__ __forceinline__ void cvt4(const float4 v, ushort4* hi, ushort4* lo) {
    unsigned short h0 = f2bf(v.x), h1 = f2bf(v.y),
                   h2 = f2bf(v.z), h3 = f2bf(v.w);
    *hi = make_ushort4(h0, h1, h2, h3);
    *lo = make_ushort4(f2bf(v.x - bf2f(h0)), f2bf(v.y - bf2f(h1)),
                       f2bf(v.z - bf2f(h2)), f2bf(v.w - bf2f(h3)));
}

// ---- prep: gate_w fp32 -> bf16 hi/lo planes in fragment-native layout ----
__global__ __launch_bounds__(256)
void prep_kernel(const float* __restrict__ gw, unsigned short* __restrict__ ws)
{
    const int gid = blockIdx.x * 256 + threadIdx.x;   // 0..32767 float4 slots
    const int e  = gid >> 9;          // 512 float4 per expert row
    const int k  = (gid & 511) * 4;
    float4 v = *(const float4*)(gw + (size_t)e * HH + k);
    ushort4 hi, lo;
    cvt4(v, &hi, &lo);
    const int off = (k >> 5) * 2048 + ((k >> 3) & 3) * 512 + e * 8 + (k & 7);
    *(ushort4*)(ws + off)           = hi;
    *(ushort4*)(ws + WSPLANE + off) = lo;
}

// ---- main: H staged in LDS (hi/lo, dbuf), B-frags direct from ws (L2) ----
// Per chunk C: 4 B global loads + stage H + barrier + 4 A ds_reads + 6 MFMA.
#define CHUNK(C, HV)                                                           \
  do {                                                                         \
    const unsigned short* bp_ = bBase + (size_t)(2 * (C)) * 2048;              \
    bf16x8 Bh0 = *(const bf16x8*)(bp_);                                        \
    bf16x8 Bl0 = *(const bf16x8*)(bp_ + WSPLANE);                              \
    bf16x8 Bh1 = *(const bf16x8*)(bp_ + 2048);                                 \
    bf16x8 Bl1 = *(const bf16x8*)(bp_ + 2048 + WSPLANE);                       \
    unsigned char* buf_ = smem + ((C) & 1) * 4096;                             \
    ushort4 hi_, lo_;                                                          \
    cvt4(HV, &hi_, &lo_);                                                      \
    *(ushort4*)(buf_ + hOff)        = hi_;                                     \
    *(ushort4*)(buf_ + 2048 + hOff) = lo_;                                     \
    __syncthreads();                                                           \
    if ((C) + 2 < NCH) HV = *(const float4*)(hgp + ((C) + 2) * HC);            \
    bf16x8 Ah0 = *(const bf16x8*)(buf_ + aOff0);                               \
    bf16x8 Al0 = *(const bf16x8*)(buf_ + 2048 + aOff0);                        \
    bf16x8 Ah1 = *(const bf16x8*)(buf_ + aOff1);                               \
    bf16x8 Al1 = *(const bf16x8*)(buf_ + 2048 + aOff1);                        \
    acc = __builtin_amdgcn_mfma_f32_16x16x32_bf16(Ah0, Bl0, acc, 0, 0, 0);     \
    acc = __builtin_amdgcn_mfma_f32_16x16x32_bf16(Al0, Bh0, acc, 0, 0, 0);     \
    acc = __builtin_amdgcn_mfma_f32_16x16x32_bf16(Ah0, Bh0, acc, 0, 0, 0);     \
    acc = __builtin_amdgcn_mfma_f32_16x16x32_bf16(Ah1, Bl1, acc, 0, 0, 0);     \
    acc = __builtin_amdgcn_mfma_f32_16x16x32_bf16(Al1, Bh1, acc, 0, 0, 0);     \
    acc = __builtin_amdgcn_mfma_f32_16x16x32_bf16(Ah1, Bh1, acc, 0, 0, 0);     \
  } while (0)

__global__ __launch_bounds__(256, 4)
void router_kernel(const float* __restrict__ hidden,
                   const float* __restrict__ gate_w,
                   const float* __restrict__ bias,
                   const unsigned short* __restrict__ wsbuf,
                   float* __restrict__ out)
{
    // dbuf H staging: buffer = [Hhi 16x128B | Hlo 16x128B] = 4096 B; x2.
    // lg overlay (16x68 f32 = 4352 B) fits in 8192 after final barrier.
    __shared__ __align__(16) unsigned char smem[8192];

    const int tid  = threadIdx.x;
    const int tok0 = blockIdx.x * TB;

    // staging coords: thread stages H row hr, float4-slot hc4 (swizzled LDS)
    const int hr  = tid >> 4;        // 0..15
    const int hc4 = tid & 15;
    const float* hgp = hidden + (size_t)(tok0 + hr) * HH + hc4 * 4;
    const int hOff = hr * 128 + ((hc4 * 8) ^ ((hr & 7) << 4));

    // fragment coords (R9-validated): rx=lane&15, kq=lane>>4, e0=wave*16
    const int lane = tid & 63;
    const int e0   = (tid >> 6) * 16;
    const int rx   = lane & 15;
    const int kq   = lane >> 4;
    const int aOff0 = rx * 128 + ((kq * 16) ^ ((rx & 7) << 4));
    const int aOff1 = aOff0 ^ 64;
    const unsigned short* bBase = wsbuf + kq * 512 + (e0 + rx) * 8;

    f32x4 acc = {0.f, 0.f, 0.f, 0.f};

    // 2-deep H prefetch ring (static names)
    float4 hvA = *(const float4*)(hgp);
    float4 hvB = *(const float4*)(hgp + HC);

    for (int c = 0; c < NCH; c += 2) {
        CHUNK(c, hvA);
        CHUNK(c + 1, hvB);
    }
    __syncthreads();   // all compute done before lg overlays buffers

    // ---- logits to LDS: row = token = 4*kq + r, col = expert = e0 + rx ----
    float* lg = (float*)smem;   // [16][68]
    #pragma unroll
    for (int r = 0; r < 4; ++r)
        lg[(4 * kq + r) * 68 + e0 + rx] = acc[r];
    __syncthreads();

    // ---- epilogue: 16 lanes per token (R9-validated machinery) ----
    const int t   = tid >> 4;   // 0..15
    const int q   = tid & 15;   // lane owns experts q + 16i, i=0..3
    const int tok = tok0 + t;

    float lv[4];
    #pragma unroll
    for (int i = 0; i < 4; ++i) lv[i] = lg[t * 68 + q + 16 * i];

    float mx = lv[0];
    #pragma unroll
    for (int i = 1; i < 4; ++i) mx = fmaxf(mx, lv[i]);
    #pragma unroll
    for (int sh = 1; sh < 16; sh <<= 1) mx = fmaxf(mx, __shfl_xor(mx, sh, 64));

    float ex[4], psum = 0.0f;
    #pragma unroll
    for (int i = 0; i < 4; ++i) { ex[i] = expf(lv[i] - mx); psum += ex[i]; }
    #pragma unroll
    for (int sh = 1; sh < 16; sh <<= 1) psum += __shfl_xor(psum, sh, 64);
    const float inv = 1.0f / psum;

    float pr[4], selv[4];
    #pragma unroll
    for (int i = 0; i < 4; ++i) {
        pr[i]   = ex[i] * inv;
        selv[i] = pr[i] + bias[q + 16 * i];
    }

    // top-10 candidates (fp32), strict-> with lowest-index tie-break
    float ws_[TOPC], wp[TOPC];
    int   wi[TOPC];
    #pragma unroll
    for (int k = 0; k < TOPC; ++k) {
        float bs = selv[0], bp = pr[0];
        int bi = q;
        #pragma unroll
        for (int i = 1; i < 4; ++i)
            if (selv[i] > bs) { bs = selv[i]; bp = pr[i]; bi = q + 16 * i; }
        #pragma unroll
        for (int sh = 1; sh < 16; sh <<= 1) {
            float os = __shfl_xor(bs, sh, 64);
            float op = __shfl_xor(bp, sh, 64);
            int   ob = __shfl_xor(bi, sh, 64);
            if (os > bs || (os == bs && ob < bi)) { bs = os; bp = op; bi = ob; }
        }
        ws_[k] = bs; wp[k] = bp; wi[k] = bi;
        #pragma unroll
        for (int i = 0; i < 4; ++i)
            if (q + 16 * i == bi) selv[i] = -INFINITY;
    }

    // flag: any adjacent gap among ranks 1..9 too small to trust bf16x3
    bool flag = false;
    #pragma unroll
    for (int k = 0; k < 8; ++k)
        flag = flag || (ws_[k] - ws_[k + 1] < MARGIN);

    if (flag) {   // uniform across the 16-lane token group
        const float* hrow = hidden + (size_t)tok * HH;
        const float* wr_[TOPC];
        #pragma unroll
        for (int k = 0; k < TOPC; ++k) wr_[k] = gate_w + (size_t)wi[k] * HH;

        double l64[TOPC];
        #pragma unroll
        for (int k = 0; k < TOPC; ++k) l64[k] = 0.0;

        for (int m = 0; m < 32; ++m) {
            float4 h4 = *(const float4*)(hrow + m * 64 + 4 * q);
            double h0 = h4.x, h1 = h4.y, h2 = h4.z, h3 = h4.w;
            #pragma unroll
            for (int k = 0; k < TOPC; ++k) {
                float4 w4 = *(const float4*)(wr_[k] + m * 64 + 4 * q);
                l64[k] = fma(h0, (double)w4.x, l64[k]);
                l64[k] = fma(h1, (double)w4.y, l64[k]);
                l64[k] = fma(h2, (double)w4.z, l64[k]);
                l64[k] = fma(h3, (double)w4.w, l64[k]);
            }
        }
        #pragma unroll
        for (int k = 0; k < TOPC; ++k)
            #pragma unroll
            for (int sh = 1; sh < 16; sh <<= 1)
                l64[k] += __shfl_xor(l64[k], sh, 64);

        // exact-rank selection scores (common positive rescale; bias exact)
        double s64[TOPC];
        #pragma unroll
        for (int k = 0; k < TOPC; ++k)
            s64[k] = exp(l64[k] - (double)mx) * (double)inv + (double)bias[wi[k]];

        // order first 8 by (score desc, idx asc) - static indices only
        #pragma unroll
        for (int a = 0; a < 8; ++a) {
            #pragma unroll
            for (int b = a + 1; b < TOPC; ++b) {
                bool sw = (s64[b] > s64[a]) ||
                          (s64[b] == s64[a] && wi[b] < wi[a]);
                if (sw) {
                    double td = s64[a]; s64[a] = s64[b]; s64[b] = td;
                    int    ti = wi[a];  wi[a]  = wi[b];  wi[b]  = ti;
                    float  tp = wp[a];  wp[a]  = wp[b];  wp[b]  = tp;
                }
            }
        }
    }

    // ---- common write-out (wi/wp[0..7] final) ----
    int oi = wi[0];
    float opf = wp[0];
    #pragma unroll
    for (int k = 1; k < 8; ++k)
        if (q == k) { oi = wi[k]; opf = wp[k]; }

    float ps = 0.0f;
    #pragma unroll
    for (int k = 0; k < 8; ++k) ps += wp[k];
    const float rinv = 1.0f / (ps + 1e-9f);

    if (q < KK) {
        out[(size_t)tok * KK + q]           = opf * rinv;
        out[IDX_OFF + (size_t)tok * KK + q] = (float)oi;
    }

    unsigned long long mk = 0ull;
    #pragma unroll
    for (int k = 0; k < 8; ++k) mk |= (1ull << wi[k]);

    {
        float4 a;
        a.x = ((mk >> (4 * q + 0)) & 1ull) ? 1.0f : 0.0f;
        a.y = ((mk >> (4 * q + 1)) & 1ull) ? 1.0f : 0.0f;
        a.z = ((mk >> (4 * q + 2)) & 1ull) ? 1.0f : 0.0f;
        a.w = ((mk >> (4 * q + 3)) & 1ull) ? 1.0f : 0.0f;
        *(float4*)(out + MAP_OFF + (size_t)tok * EE + 4 * q) = a;
    }

    if (blockIdx.x == 0 && tid == 0) out[AUX_OFF] = 0.0f;
}

extern "C" void kernel_launch(void* const* d_in, const int* in_sizes, int n_in,
                              void* d_out, int out_size, void* d_ws, size_t ws_size,
                              hipStream_t stream) {
    const float* hidden = (const float*)d_in[0];  // [16384, 2048] f32
    const float* gate_w = (const float*)d_in[1];  // [64, 2048] f32
    const float* bias   = (const float*)d_in[2];  // [64] f32
    float* out = (float*)d_out;
    unsigned short* ws = (unsigned short*)d_ws;   // needs 512 KB

    prep_kernel<<<128, 256, 0, stream>>>(gate_w, ws);
    router_kernel<<<TT / TB, 256, 0, stream>>>(hidden, gate_w, bias, ws, out);
}